// Round 1
// baseline (4187.054 us; speedup 1.0000x reference)
//
#include <hip/hip_runtime.h>
#include <hip/hip_bf16.h>
#include <hip/hip_cooperative_groups.h>
#include <math.h>

namespace cg = cooperative_groups;

// Observer recurrence -> LTI Markov-parameter convolution (W-only chain).
//   A' = A - L*C, K = [B - L*D | L | h0], W_m = A'^m K, f_m = C*W_m
//   y_t = f_t[9] + D*u_t + sum_j f_j . z_{t-1-j};  out = 3*tanh(y)
// Round-9 change vs round-8: the 55 k_stepW launches (each re-reading the
// 32 MB swizzled A' from HBM ~= 1.9 GB total + ~90 us dispatch overhead) are
// replaced by ONE persistent cooperative kernel. 256 blocks x 512 thr,
// 1 block/CU: each block stages its contiguous 128 KB A'-panel into LDS once
// (32 MB one-time HBM read; full matrix lives in 256 CUs x 128 KB LDS) and
// the whole 55-step chain runs with cg grid.sync() between steps. Per-step
// global traffic is only the 128 KB Wh broadcast + ~384 KB W writes
// (+ 32 MB Al for the 6 seed steps). Same math as r8: swizzled fragment
// order, split-precision seeds, JT=56, SEEDS=6 (absmax 0.039 vs 0.06).

constexpr int NDIM  = 4096;
constexpr int NC    = 10;         // live columns of K/W
constexpr int SLAB  = 16 * 4096;  // padded 16-col col-major slab (elements)
constexpr int JT    = 56;         // truncation length
constexpr int SEEDS = 6;          // split-precision seed steps
constexpr int KC    = NDIM / 32;  // 128 k-chunks of 32
constexpr int TILES = NDIM / 16;  // 256 row-tiles of 16

typedef float f32x4  __attribute__((ext_vector_type(4)));
typedef short short8 __attribute__((ext_vector_type(8)));

// ---------- build A' split bf16, swizzled to fragment order ----------
// AhSw element (short8): idx = (tile*KC + kc)*64 + lane
//   lane = mr + 16q holds A'[tile*16+mr][kc*32 + q*8 .. +7]
__global__ __launch_bounds__(256) void k_build_a(
        const float* __restrict__ A, const float* __restrict__ C,
        const float* __restrict__ L,
        short8* __restrict__ AhSw, short8* __restrict__ AlSw) {
    const size_t idx = (size_t)blockIdx.x * blockDim.x + threadIdx.x; // < TILES*KC*64
    const int lane = (int)(idx & 63);
    const int kc   = (int)((idx >> 6) & (KC - 1));
    const int tile = (int)(idx >> 13);
    const int row  = tile * 16 + (lane & 15);
    const int col  = kc * 32 + (lane >> 4) * 8;
    const float4 a0 = *(const float4*)(A + (size_t)row * NDIM + col);
    const float4 a1 = *(const float4*)(A + (size_t)row * NDIM + col + 4);
    const float Li = L[row];
    float v[8] = { a0.x - Li * C[col + 0], a0.y - Li * C[col + 1],
                   a0.z - Li * C[col + 2], a0.w - Li * C[col + 3],
                   a1.x - Li * C[col + 4], a1.y - Li * C[col + 5],
                   a1.z - Li * C[col + 6], a1.w - Li * C[col + 7] };
    union { short8 s8; __hip_bfloat16 h[8]; } hi, lo;
    #pragma unroll
    for (int s = 0; s < 8; ++s) {
        hi.h[s] = __float2bfloat16(v[s]);
        lo.h[s] = __float2bfloat16(v[s] - __bfloat162float(hi.h[s]));
    }
    AhSw[idx] = hi.s8;
    AlSw[idx] = lo.s8;
}

// ---------- W0 = K = [B-L*D | L | ones | 0-pad], fp32 + split bf16 ----------
__global__ __launch_bounds__(256) void k_build_w0(
        const float* __restrict__ Bm, const float* __restrict__ Dm,
        const float* __restrict__ L, float* __restrict__ Wf,
        __hip_bfloat16* __restrict__ Wh, __hip_bfloat16* __restrict__ Wl) {
    int k = blockIdx.x * blockDim.x + threadIdx.x; // < 4096
    float Lk = L[k];
    float col[16];
    #pragma unroll
    for (int c = 0; c < 8; ++c) col[c] = Bm[k * 8 + c] - Lk * Dm[c];
    col[8] = Lk; col[9] = 1.0f;
    #pragma unroll
    for (int c = 10; c < 16; ++c) col[c] = 0.0f;
    #pragma unroll
    for (int c = 0; c < 16; ++c) {
        Wf[c * NDIM + k] = col[c];
        __hip_bfloat16 h = __float2bfloat16(col[c]);
        Wh[c * NDIM + k] = h;
        Wl[c * NDIM + k] = __float2bfloat16(col[c] - __bfloat162float(h));
    }
}

// ---------- persistent chain: all 55 steps, A' resident in LDS ----------
// 256 blocks (1/CU) x 512 thr (8 waves, k-split 8x512). Wave w: kc-local
// [w*16, w*16+16). A-load: LDS ds_read_b128 (contiguous 1 KB per wave instr).
// Seeds additionally read AlSw from global (L2/L3-served).
// One grid.sync() per step; W slabs are per-m distinct so a single barrier
// per step (write m+1 -> sync -> read m+1) is race-free.
__global__ __launch_bounds__(512) void k_chain(
        const short8* __restrict__ AhSw, const short8* __restrict__ AlSw,
        float* __restrict__ Wf, __hip_bfloat16* __restrict__ Wh,
        __hip_bfloat16* __restrict__ Wl) {
    __shared__ short8 Alds[KC * 64];   // 128 KiB: this tile's A'hi, frag order
    __shared__ f32x4  red[8][64];      // 8 KiB reduction buffer
    const int tid  = threadIdx.x;
    const int lane = tid & 63, wave = tid >> 6;   // wave 0..7
    const int mr   = lane & 15, q = lane >> 4;
    const int tile = blockIdx.x;
    const int row0 = tile * 16;
    const int k0   = wave * 512;

    // one-time stage: contiguous 128 KiB global -> LDS
    {
        const short8* src = AhSw + (size_t)tile * (KC * 64);
        for (int idx = tid; idx < KC * 64; idx += 512) Alds[idx] = src[idx];
    }
    __syncthreads();

    const short8* la  = Alds + wave * 16 * 64 + lane;                       // LDS
    const short8* al8 = AlSw + ((size_t)tile * KC + wave * 16) * 64 + lane; // global

    cg::grid_group grid = cg::this_grid();

    for (int m = 0; m < JT - 1; ++m) {
        const short8* b8 = (const short8*)(Wh + (size_t)m * SLAB)
                         + (((size_t)mr * NDIM + k0) >> 3) + q;
        f32x4 acc0 = {0,0,0,0}, acc1 = {0,0,0,0}, accS = {0,0,0,0};
        if (m < SEEDS) {
            const short8* bl8 = (const short8*)(Wl + (size_t)m * SLAB)
                              + (((size_t)mr * NDIM + k0) >> 3) + q;
            for (int it = 0; it < 4; ++it) {
                short8 ra[4], rb[4], rla[4], rlb[4];
                #pragma unroll
                for (int s = 0; s < 4; ++s) {
                    const int c = it * 4 + s;            // kc-local 0..15
                    ra[s]  = la[c * 64];
                    rla[s] = al8[(size_t)c * 64];
                    rb[s]  = b8[c * 4];
                    rlb[s] = bl8[c * 4];
                }
                #pragma unroll
                for (int s = 0; s < 4; ++s) {
                    if (s & 1) acc1 = __builtin_amdgcn_mfma_f32_16x16x32_bf16(ra[s], rb[s], acc1, 0, 0, 0);
                    else       acc0 = __builtin_amdgcn_mfma_f32_16x16x32_bf16(ra[s], rb[s], acc0, 0, 0, 0);
                    accS = __builtin_amdgcn_mfma_f32_16x16x32_bf16(ra[s], rlb[s], accS, 0, 0, 0);
                    accS = __builtin_amdgcn_mfma_f32_16x16x32_bf16(rla[s], rb[s], accS, 0, 0, 0);
                }
            }
        } else {
            for (int it = 0; it < 2; ++it) {
                short8 ra[8], rb[8];
                #pragma unroll
                for (int s = 0; s < 8; ++s) {
                    const int c = it * 8 + s;            // kc-local 0..15
                    ra[s] = la[c * 64];
                    rb[s] = b8[c * 4];
                }
                #pragma unroll
                for (int s = 0; s < 8; ++s) {
                    if (s & 1) acc1 = __builtin_amdgcn_mfma_f32_16x16x32_bf16(ra[s], rb[s], acc1, 0, 0, 0);
                    else       acc0 = __builtin_amdgcn_mfma_f32_16x16x32_bf16(ra[s], rb[s], acc0, 0, 0, 0);
                }
            }
        }
        red[wave][lane] = acc0 + acc1 + accS;
        __syncthreads();
        if (tid < 64) {
            f32x4 v = red[0][tid] + red[1][tid] + red[2][tid] + red[3][tid]
                    + red[4][tid] + red[5][tid] + red[6][tid] + red[7][tid];
            const int col = tid & 15;
            const int rb0 = row0 + ((tid >> 4) << 2);
            float*          wf = Wf + (size_t)(m + 1) * SLAB;
            __hip_bfloat16* wh = Wh + (size_t)(m + 1) * SLAB;
            __hip_bfloat16* wl = Wl + (size_t)(m + 1) * SLAB;
            #pragma unroll
            for (int i = 0; i < 4; ++i) {
                wf[col * NDIM + rb0 + i] = v[i];
                __hip_bfloat16 h = __float2bfloat16(v[i]);
                wh[col * NDIM + rb0 + i] = h;
                if (m < SEEDS) wl[col * NDIM + rb0 + i] =
                    __float2bfloat16(v[i] - __bfloat162float(h));
            }
        }
        __threadfence();   // device-scope release of W writes (cross-XCD)
        grid.sync();       // also covers the block-local red[] WAR hazard
    }
}

// ---------- f_m = C . W_m for all m ----------
__global__ __launch_bounds__(256) void k_fbatch(
        const float* __restrict__ Wall, const float* __restrict__ C,
        float* __restrict__ F) {
    const int m = blockIdx.x;
    const float* W = Wall + (size_t)m * SLAB;
    const int tid = threadIdx.x, lane = tid & 63, wave = tid >> 6;
    float acc[NC] = {};
    for (int k = tid; k < NDIM; k += 256) {
        float ck = C[k];
        #pragma unroll
        for (int c = 0; c < NC; ++c) acc[c] += ck * W[c * NDIM + k];
    }
    __shared__ float red[4][NC];
    #pragma unroll
    for (int c = 0; c < NC; ++c) {
        float s = acc[c];
        #pragma unroll
        for (int off = 32; off > 0; off >>= 1) s += __shfl_down(s, off);
        if (lane == 0) red[wave][c] = s;
    }
    __syncthreads();
    if (tid < NC) F[m * NC + tid] = red[0][tid] + red[1][tid] + red[2][tid] + red[3][tid];
}

// ---------- causal convolution + tanh epilogue ----------
__global__ __launch_bounds__(256) void k_conv(
        const float* __restrict__ F, const float* __restrict__ u,
        const float* __restrict__ yobs, const float* __restrict__ Dm,
        float* __restrict__ out) {
    __shared__ float Fl[JT * NC];
    __shared__ float zw[(JT + 256) * 9];
    const int tid = threadIdx.x;
    const int t0  = blockIdx.x * 256;
    for (int idx = tid; idx < JT * NC; idx += 256) Fl[idx] = F[idx];
    for (int idx = tid; idx < (JT + 256) * 9; idx += 256) {
        int k = idx / 9, c = idx - k * 9;
        int s = t0 - JT + k;
        float v = 0.0f;
        if (s >= 0 && s < NDIM) v = (c < 8) ? u[c * NDIM + s] : yobs[s];
        zw[idx] = v;
    }
    __syncthreads();
    const int t = t0 + tid;
    float y = (t < JT) ? Fl[t * NC + 9] : 0.0f; // C A'^t h0 term (truncated)
    #pragma unroll
    for (int c = 0; c < 8; ++c) y += Dm[c] * u[c * NDIM + t];
    for (int j = 0; j < JT; ++j) { // s = t-1-j; s<0 hits zero pad
        const float* fj = Fl + j * NC;
        const float* zz = zw + (tid + JT - 1 - j) * 9;
        float p = 0.0f;
        #pragma unroll
        for (int c = 0; c < 9; ++c) p += fj[c] * zz[c];
        y += p;
    }
    out[t] = 3.0f * tanhf(y);
}

extern "C" void kernel_launch(void* const* d_in, const int* in_sizes, int n_in,
                              void* d_out, int out_size, void* d_ws, size_t ws_size,
                              hipStream_t stream) {
    const float* u    = (const float*)d_in[0];
    const float* yobs = (const float*)d_in[1];
    const float* A    = (const float*)d_in[2];
    const float* Bm   = (const float*)d_in[3];
    const float* C    = (const float*)d_in[4];
    const float* Dm   = (const float*)d_in[5];
    const float* L    = (const float*)d_in[6];
    float* out = (float*)d_out;

    // workspace layout (~91 MB)
    char* ws = (char*)d_ws;
    short8*         AhSw = (short8*)ws;                              // 32 MB
    short8*         AlSw = (short8*)(ws + 33554432ull);              // 32 MB
    float*          Wf   = (float*)(ws + 67108864ull);               // 56*256 KB
    __hip_bfloat16* Wh   = (__hip_bfloat16*)(ws + 81788928ull);      // 56*128 KB
    __hip_bfloat16* Wl   = (__hip_bfloat16*)(ws + 89128960ull);      // 7*128 KB
    float*          F    = (float*)(ws + 90046464ull);               // 2.24 KB

    k_build_a<<<dim3(TILES * KC * 64 / 256), dim3(256), 0, stream>>>(A, C, L, AhSw, AlSw);
    k_build_w0<<<dim3(16), dim3(256), 0, stream>>>(Bm, Dm, L, Wf, Wh, Wl);

    {
        void* args[] = { (void*)&AhSw, (void*)&AlSw, (void*)&Wf, (void*)&Wh, (void*)&Wl };
        hipLaunchCooperativeKernel((const void*)k_chain, dim3(TILES), dim3(512),
                                   args, 0u, stream);
    }

    k_fbatch<<<dim3(JT), dim3(256), 0, stream>>>(Wf, C, F);
    k_conv<<<dim3(16), dim3(256), 0, stream>>>(F, u, yobs, Dm, out);
}

// Round 2
// 557.980 us; speedup vs baseline: 7.5040x; 7.5040x over previous
//
#include <hip/hip_runtime.h>
#include <hip/hip_bf16.h>
#include <math.h>

// Observer recurrence -> LTI Markov-parameter convolution (W-only chain).
//   A' = A - L*C, K = [B - L*D | L | h0], W_m = A'^m K, f_m = C*W_m
//   y_t = f_t[9] + D*u_t + sum_j f_j . z_{t-1-j};  out = 3*tanh(y)
// Round-10: revert the cooperative persistent kernel (r9: grid.sync() costs
// ~75 us/step on MI355X -- device-scope fence forces per-XCD L2 flush; chain
// went 347us -> 4157us). Multi-launch IS the cheap barrier here (~1.5us gap).
// Change vs r8: k_stepW goes 256 -> 512 threads (8 waves, k-split 8x512).
// r8 ran 4 waves/CU with ~32KB/CU in flight -> steps at 4.4 TB/s (70% of
// ceiling). 8 waves/CU doubles memory-level parallelism. The 8-wave inner
// loop + reduction is numerically identical to the r9 coop kernel, which
// passed at absmax 0.0352. JT=56, SEEDS=6 unchanged.

constexpr int NDIM  = 4096;
constexpr int NC    = 10;         // live columns of K/W
constexpr int SLAB  = 16 * 4096;  // padded 16-col col-major slab (elements)
constexpr int JT    = 56;         // truncation length
constexpr int SEEDS = 6;          // split-precision seed steps
constexpr int KC    = NDIM / 32;  // 128 k-chunks of 32
constexpr int TILES = NDIM / 16;  // 256 row-tiles of 16

typedef float f32x4  __attribute__((ext_vector_type(4)));
typedef short short8 __attribute__((ext_vector_type(8)));

// ---------- build A' split bf16, swizzled to fragment order ----------
// AhSw element (short8): idx = (tile*KC + kc)*64 + lane
//   lane = mr + 16q holds A'[tile*16+mr][kc*32 + q*8 .. +7]
__global__ __launch_bounds__(256) void k_build_a(
        const float* __restrict__ A, const float* __restrict__ C,
        const float* __restrict__ L,
        short8* __restrict__ AhSw, short8* __restrict__ AlSw) {
    const size_t idx = (size_t)blockIdx.x * blockDim.x + threadIdx.x; // < TILES*KC*64
    const int lane = (int)(idx & 63);
    const int kc   = (int)((idx >> 6) & (KC - 1));
    const int tile = (int)(idx >> 13);
    const int row  = tile * 16 + (lane & 15);
    const int col  = kc * 32 + (lane >> 4) * 8;
    const float4 a0 = *(const float4*)(A + (size_t)row * NDIM + col);
    const float4 a1 = *(const float4*)(A + (size_t)row * NDIM + col + 4);
    const float Li = L[row];
    float v[8] = { a0.x - Li * C[col + 0], a0.y - Li * C[col + 1],
                   a0.z - Li * C[col + 2], a0.w - Li * C[col + 3],
                   a1.x - Li * C[col + 4], a1.y - Li * C[col + 5],
                   a1.z - Li * C[col + 6], a1.w - Li * C[col + 7] };
    union { short8 s8; __hip_bfloat16 h[8]; } hi, lo;
    #pragma unroll
    for (int s = 0; s < 8; ++s) {
        hi.h[s] = __float2bfloat16(v[s]);
        lo.h[s] = __float2bfloat16(v[s] - __bfloat162float(hi.h[s]));
    }
    AhSw[idx] = hi.s8;
    AlSw[idx] = lo.s8;
}

// ---------- W0 = K = [B-L*D | L | ones | 0-pad], fp32 + split bf16 ----------
__global__ __launch_bounds__(256) void k_build_w0(
        const float* __restrict__ Bm, const float* __restrict__ Dm,
        const float* __restrict__ L, float* __restrict__ Wf,
        __hip_bfloat16* __restrict__ Wh, __hip_bfloat16* __restrict__ Wl) {
    int k = blockIdx.x * blockDim.x + threadIdx.x; // < 4096
    float Lk = L[k];
    float col[16];
    #pragma unroll
    for (int c = 0; c < 8; ++c) col[c] = Bm[k * 8 + c] - Lk * Dm[c];
    col[8] = Lk; col[9] = 1.0f;
    #pragma unroll
    for (int c = 10; c < 16; ++c) col[c] = 0.0f;
    #pragma unroll
    for (int c = 0; c < 16; ++c) {
        Wf[c * NDIM + k] = col[c];
        __hip_bfloat16 h = __float2bfloat16(col[c]);
        Wh[c * NDIM + k] = h;
        Wl[c * NDIM + k] = __float2bfloat16(col[c] - __bfloat162float(h));
    }
}

// ---------- one W-chain step: W_{m+1} = A' W_m (swizzled A) ----------
// 256 blocks x 512 thr (8 waves, k-split 8x512). Wave w: kc-local
// [w*16, w*16+16). A-load: contiguous 1 KB per wave instruction.
// 8 waves/CU doubles in-flight bytes vs r8's 4 (MLP was the limiter).
// D-frag: col = lane&15, row = (lane>>4)*4 + i (validated rounds 2-9).
template <bool SEED>
__global__ __launch_bounds__(512, 1) void k_stepW(
        const short8* __restrict__ AhSw, const short8* __restrict__ AlSw,
        const __hip_bfloat16* __restrict__ WhIn, const __hip_bfloat16* __restrict__ WlIn,
        float* __restrict__ WfOut, __hip_bfloat16* __restrict__ WhOut,
        __hip_bfloat16* __restrict__ WlOut) {
    __shared__ f32x4 red[8][64];
    const int tid  = threadIdx.x;
    const int lane = tid & 63, wave = tid >> 6;   // wave 0..7
    const int mr   = lane & 15, q = lane >> 4;
    const int tile = blockIdx.x;
    const int row0 = tile * 16;
    const int k0   = wave * 512;
    const short8* a8 = AhSw + ((size_t)tile * KC + wave * 16) * 64 + lane;
    const short8* b8 = (const short8*)WhIn + (((size_t)mr * NDIM + k0) >> 3) + q;

    f32x4 acc0 = {0,0,0,0}, acc1 = {0,0,0,0}, accS = {0,0,0,0};
    if (SEED) {
        const short8* al8 = AlSw + ((size_t)tile * KC + wave * 16) * 64 + lane;
        const short8* bl8 = (const short8*)WlIn + (((size_t)mr * NDIM + k0) >> 3) + q;
        for (int it = 0; it < 4; ++it) {
            short8 ra[4], rb[4], rla[4], rlb[4];
            #pragma unroll
            for (int s = 0; s < 4; ++s) {
                const int c = it * 4 + s;            // kc-local 0..15
                ra[s]  = a8[(size_t)c * 64];
                rla[s] = al8[(size_t)c * 64];
                rb[s]  = b8[c * 4];
                rlb[s] = bl8[c * 4];
            }
            #pragma unroll
            for (int s = 0; s < 4; ++s) {
                if (s & 1) acc1 = __builtin_amdgcn_mfma_f32_16x16x32_bf16(ra[s], rb[s], acc1, 0, 0, 0);
                else       acc0 = __builtin_amdgcn_mfma_f32_16x16x32_bf16(ra[s], rb[s], acc0, 0, 0, 0);
                accS = __builtin_amdgcn_mfma_f32_16x16x32_bf16(ra[s], rlb[s], accS, 0, 0, 0);
                accS = __builtin_amdgcn_mfma_f32_16x16x32_bf16(rla[s], rb[s], accS, 0, 0, 0);
            }
        }
    } else {
        for (int it = 0; it < 2; ++it) {
            short8 ra[8], rb[8];
            #pragma unroll
            for (int s = 0; s < 8; ++s) {
                const int c = it * 8 + s;            // kc-local 0..15
                ra[s] = a8[(size_t)c * 64];
                rb[s] = b8[c * 4];
            }
            #pragma unroll
            for (int s = 0; s < 8; ++s) {
                if (s & 1) acc1 = __builtin_amdgcn_mfma_f32_16x16x32_bf16(ra[s], rb[s], acc1, 0, 0, 0);
                else       acc0 = __builtin_amdgcn_mfma_f32_16x16x32_bf16(ra[s], rb[s], acc0, 0, 0, 0);
            }
        }
    }
    red[wave][lane] = acc0 + acc1 + accS;
    __syncthreads();
    if (tid < 64) {
        f32x4 v = red[0][tid] + red[1][tid] + red[2][tid] + red[3][tid]
                + red[4][tid] + red[5][tid] + red[6][tid] + red[7][tid];
        const int col = tid & 15;
        const int rb0 = row0 + ((tid >> 4) << 2);
        #pragma unroll
        for (int i = 0; i < 4; ++i) {
            WfOut[col * NDIM + rb0 + i] = v[i];
            __hip_bfloat16 h = __float2bfloat16(v[i]);
            WhOut[col * NDIM + rb0 + i] = h;
            if (SEED) WlOut[col * NDIM + rb0 + i] =
                __float2bfloat16(v[i] - __bfloat162float(h));
        }
    }
}

// ---------- f_m = C . W_m for all m ----------
__global__ __launch_bounds__(256) void k_fbatch(
        const float* __restrict__ Wall, const float* __restrict__ C,
        float* __restrict__ F) {
    const int m = blockIdx.x;
    const float* W = Wall + (size_t)m * SLAB;
    const int tid = threadIdx.x, lane = tid & 63, wave = tid >> 6;
    float acc[NC] = {};
    for (int k = tid; k < NDIM; k += 256) {
        float ck = C[k];
        #pragma unroll
        for (int c = 0; c < NC; ++c) acc[c] += ck * W[c * NDIM + k];
    }
    __shared__ float red[4][NC];
    #pragma unroll
    for (int c = 0; c < NC; ++c) {
        float s = acc[c];
        #pragma unroll
        for (int off = 32; off > 0; off >>= 1) s += __shfl_down(s, off);
        if (lane == 0) red[wave][c] = s;
    }
    __syncthreads();
    if (tid < NC) F[m * NC + tid] = red[0][tid] + red[1][tid] + red[2][tid] + red[3][tid];
}

// ---------- causal convolution + tanh epilogue ----------
__global__ __launch_bounds__(256) void k_conv(
        const float* __restrict__ F, const float* __restrict__ u,
        const float* __restrict__ yobs, const float* __restrict__ Dm,
        float* __restrict__ out) {
    __shared__ float Fl[JT * NC];
    __shared__ float zw[(JT + 256) * 9];
    const int tid = threadIdx.x;
    const int t0  = blockIdx.x * 256;
    for (int idx = tid; idx < JT * NC; idx += 256) Fl[idx] = F[idx];
    for (int idx = tid; idx < (JT + 256) * 9; idx += 256) {
        int k = idx / 9, c = idx - k * 9;
        int s = t0 - JT + k;
        float v = 0.0f;
        if (s >= 0 && s < NDIM) v = (c < 8) ? u[c * NDIM + s] : yobs[s];
        zw[idx] = v;
    }
    __syncthreads();
    const int t = t0 + tid;
    float y = (t < JT) ? Fl[t * NC + 9] : 0.0f; // C A'^t h0 term (truncated)
    #pragma unroll
    for (int c = 0; c < 8; ++c) y += Dm[c] * u[c * NDIM + t];
    for (int j = 0; j < JT; ++j) { // s = t-1-j; s<0 hits zero pad
        const float* fj = Fl + j * NC;
        const float* zz = zw + (tid + JT - 1 - j) * 9;
        float p = 0.0f;
        #pragma unroll
        for (int c = 0; c < 9; ++c) p += fj[c] * zz[c];
        y += p;
    }
    out[t] = 3.0f * tanhf(y);
}

extern "C" void kernel_launch(void* const* d_in, const int* in_sizes, int n_in,
                              void* d_out, int out_size, void* d_ws, size_t ws_size,
                              hipStream_t stream) {
    const float* u    = (const float*)d_in[0];
    const float* yobs = (const float*)d_in[1];
    const float* A    = (const float*)d_in[2];
    const float* Bm   = (const float*)d_in[3];
    const float* C    = (const float*)d_in[4];
    const float* Dm   = (const float*)d_in[5];
    const float* L    = (const float*)d_in[6];
    float* out = (float*)d_out;

    // workspace layout (~91 MB)
    char* ws = (char*)d_ws;
    short8*         AhSw = (short8*)ws;                              // 32 MB
    short8*         AlSw = (short8*)(ws + 33554432ull);              // 32 MB
    float*          Wf   = (float*)(ws + 67108864ull);               // 56*256 KB
    __hip_bfloat16* Wh   = (__hip_bfloat16*)(ws + 81788928ull);      // 56*128 KB
    __hip_bfloat16* Wl   = (__hip_bfloat16*)(ws + 89128960ull);      // 7*128 KB
    float*          F    = (float*)(ws + 90046464ull);               // 2.24 KB

    k_build_a<<<dim3(TILES * KC * 64 / 256), dim3(256), 0, stream>>>(A, C, L, AhSw, AlSw);
    k_build_w0<<<dim3(16), dim3(256), 0, stream>>>(Bm, Dm, L, Wf, Wh, Wl);

    for (int m = 0; m < JT - 1; ++m) {
        const size_t in  = (size_t)m * SLAB;
        const size_t out_ = (size_t)(m + 1) * SLAB;
        if (m < SEEDS)
            k_stepW<true><<<dim3(TILES), dim3(512), 0, stream>>>(
                AhSw, AlSw, Wh + in, Wl + in,
                Wf + out_, Wh + out_, Wl + out_);
        else
            k_stepW<false><<<dim3(TILES), dim3(512), 0, stream>>>(
                AhSw, nullptr, Wh + in, nullptr,
                Wf + out_, Wh + out_, nullptr);
    }

    k_fbatch<<<dim3(JT), dim3(256), 0, stream>>>(Wf, C, F);
    k_conv<<<dim3(16), dim3(256), 0, stream>>>(F, u, yobs, Dm, out);
}

// Round 3
// 533.105 us; speedup vs baseline: 7.8541x; 1.0467x over previous
//
#include <hip/hip_runtime.h>
#include <hip/hip_bf16.h>
#include <math.h>

// Observer recurrence -> LTI Markov-parameter convolution.
//   A' = A - L*C, K = [B - L*D | L | h0], f_m = C A'^m K
//   y_t = f_t[9] + D*u_t + sum_j f_j . z_{t-1-j};  out = 3*tanh(y)
// Round-11: meet-in-the-middle split. f_{i+j} = (C A'^i) . (A'^j K):
//   V-chain: W_j = A'^j K, j=0..28 (existing MFMA step kernel, 256 blocks)
//   R-chain: g_i^T = C A'^i, i=0..27 (VALU matvec vs plain-transposed bf16
//            A'; g carried in fp32 -> only A-quantization noise per step)
// Both chains are independent -> fused into ONE launch (512 blocks), so the
// 55 dependent launches become 28. Total A-traffic unchanged (~1.8 GB);
// launch/drain overhead halves; chain depth halves (accuracy margin up).
// f_m: m<=28 via C.W_m (identical to r8 path); m=28+i via g_i.W_28.
// V-side inner loop is r8's validated 256-thread shape (4 waves, k-split
// 4x1024); r10 showed 8 waves is not better. JT=56, SEEDS=6 unchanged.

constexpr int NDIM  = 4096;
constexpr int NC    = 10;         // live columns of K/W
constexpr int SLAB  = 16 * 4096;  // padded 16-col col-major slab (elements)
constexpr int JT    = 56;         // truncation length
constexpr int SEEDS = 6;          // split-precision seed steps (V-chain)
constexpr int VAPPS = 28;         // V-chain applications (W_1..W_28)
constexpr int RAPPS = 27;         // R-chain applications (g_1..g_27)
constexpr int KC    = NDIM / 32;  // 128 k-chunks of 32
constexpr int TILES = NDIM / 16;  // 256 row-tiles of 16

typedef float f32x4  __attribute__((ext_vector_type(4)));
typedef short short8 __attribute__((ext_vector_type(8)));

// ---------- build A' split bf16, swizzled to fragment order ----------
// AhSw element (short8): idx = (tile*KC + kc)*64 + lane
//   lane = mr + 16q holds A'[tile*16+mr][kc*32 + q*8 .. +7]
__global__ __launch_bounds__(256) void k_build_a(
        const float* __restrict__ A, const float* __restrict__ C,
        const float* __restrict__ L,
        short8* __restrict__ AhSw, short8* __restrict__ AlSw) {
    const size_t idx = (size_t)blockIdx.x * blockDim.x + threadIdx.x; // < TILES*KC*64
    const int lane = (int)(idx & 63);
    const int kc   = (int)((idx >> 6) & (KC - 1));
    const int tile = (int)(idx >> 13);
    const int row  = tile * 16 + (lane & 15);
    const int col  = kc * 32 + (lane >> 4) * 8;
    const float4 a0 = *(const float4*)(A + (size_t)row * NDIM + col);
    const float4 a1 = *(const float4*)(A + (size_t)row * NDIM + col + 4);
    const float Li = L[row];
    float v[8] = { a0.x - Li * C[col + 0], a0.y - Li * C[col + 1],
                   a0.z - Li * C[col + 2], a0.w - Li * C[col + 3],
                   a1.x - Li * C[col + 4], a1.y - Li * C[col + 5],
                   a1.z - Li * C[col + 6], a1.w - Li * C[col + 7] };
    union { short8 s8; __hip_bfloat16 h[8]; } hi, lo;
    #pragma unroll
    for (int s = 0; s < 8; ++s) {
        hi.h[s] = __float2bfloat16(v[s]);
        lo.h[s] = __float2bfloat16(v[s] - __bfloat162float(hi.h[s]));
    }
    AhSw[idx] = hi.s8;
    AlSw[idx] = lo.s8;
}

// ---------- build At = (A')^T, plain row-major bf16 (for the g matvec) ----
// At[c][r] = A[r][c] - L[r]*C[c]. Tiled 64x64 transpose through LDS.
__global__ __launch_bounds__(256) void k_build_at(
        const float* __restrict__ A, const float* __restrict__ C,
        const float* __restrict__ L, __hip_bfloat16* __restrict__ At) {
    __shared__ float lds[64][65];
    const int R0 = (blockIdx.x & 63) * 64;   // A row-block
    const int C0 = (blockIdx.x >> 6) * 64;   // A col-block
    const int tid = threadIdx.x;
    #pragma unroll
    for (int it = 0; it < 16; ++it) {
        const int r = it * 4 + (tid >> 6);
        const int c = tid & 63;
        lds[r][c] = A[(size_t)(R0 + r) * NDIM + C0 + c];
    }
    __syncthreads();
    #pragma unroll
    for (int it = 0; it < 16; ++it) {
        const int c = it * 4 + (tid >> 6);
        const int r = tid & 63;
        const float v = lds[r][c] - L[R0 + r] * C[C0 + c];
        At[(size_t)(C0 + c) * NDIM + R0 + r] = __float2bfloat16(v);
    }
}

// ---------- W0 = K = [B-L*D | L | ones | 0-pad], fp32 + split bf16; g0=C --
__global__ __launch_bounds__(256) void k_build_w0(
        const float* __restrict__ Bm, const float* __restrict__ Dm,
        const float* __restrict__ L, const float* __restrict__ C,
        float* __restrict__ Wf, __hip_bfloat16* __restrict__ Wh,
        __hip_bfloat16* __restrict__ Wl, float* __restrict__ gf) {
    int k = blockIdx.x * blockDim.x + threadIdx.x; // < 4096
    float Lk = L[k];
    float col[16];
    #pragma unroll
    for (int c = 0; c < 8; ++c) col[c] = Bm[k * 8 + c] - Lk * Dm[c];
    col[8] = Lk; col[9] = 1.0f;
    #pragma unroll
    for (int c = 10; c < 16; ++c) col[c] = 0.0f;
    #pragma unroll
    for (int c = 0; c < 16; ++c) {
        Wf[c * NDIM + k] = col[c];
        __hip_bfloat16 h = __float2bfloat16(col[c]);
        Wh[c * NDIM + k] = h;
        Wl[c * NDIM + k] = __float2bfloat16(col[c] - __bfloat162float(h));
    }
    gf[k] = C[k];   // g_0 = C
}

// ---------- fused step: V-role (blocks 0..255) + R-role (blocks 256..511) --
// V: W_{m+1} = A' W_m, r8's validated 256-thr shape (4 waves, k-split 4x1024).
// R: g_{r+1}[k'] = sum_k At[k'][k] * g_r[k], fp32 carry, bf16 At rows.
template <bool SEED>
__global__ __launch_bounds__(256) void k_stepVR(
        const short8* __restrict__ AhSw, const short8* __restrict__ AlSw,
        const __hip_bfloat16* __restrict__ WhIn, const __hip_bfloat16* __restrict__ WlIn,
        float* __restrict__ WfOut, __hip_bfloat16* __restrict__ WhOut,
        __hip_bfloat16* __restrict__ WlOut,
        const __hip_bfloat16* __restrict__ At, const float* __restrict__ gIn,
        float* __restrict__ gOut, const int doR) {
    __shared__ f32x4 red[4][64];
    const int tid = threadIdx.x;

    if (blockIdx.x < 256) {
        // ---------------- V role ----------------
        const int lane = tid & 63, wave = tid >> 6;
        const int mr   = lane & 15, q = lane >> 4;
        const int tile = blockIdx.x;
        const int row0 = tile * 16;
        const int k0   = wave * 1024;
        const short8* a8 = AhSw + ((size_t)tile * KC + wave * 32) * 64 + lane;
        const short8* b8 = (const short8*)WhIn + (((size_t)mr * NDIM + k0) >> 3) + q;

        f32x4 acc0 = {0,0,0,0}, acc1 = {0,0,0,0}, accS = {0,0,0,0};
        if (SEED) {
            const short8* al8 = AlSw + ((size_t)tile * KC + wave * 32) * 64 + lane;
            const short8* bl8 = (const short8*)WlIn + (((size_t)mr * NDIM + k0) >> 3) + q;
            for (int it = 0; it < 8; ++it) {
                short8 ra[4], rb[4], rla[4], rlb[4];
                #pragma unroll
                for (int s = 0; s < 4; ++s) {
                    const int c = it * 4 + s;           // kc-local 0..31
                    ra[s]  = a8[(size_t)c * 64];
                    rla[s] = al8[(size_t)c * 64];
                    rb[s]  = b8[c * 4];
                    rlb[s] = bl8[c * 4];
                }
                #pragma unroll
                for (int s = 0; s < 4; ++s) {
                    if (s & 1) acc1 = __builtin_amdgcn_mfma_f32_16x16x32_bf16(ra[s], rb[s], acc1, 0, 0, 0);
                    else       acc0 = __builtin_amdgcn_mfma_f32_16x16x32_bf16(ra[s], rb[s], acc0, 0, 0, 0);
                    accS = __builtin_amdgcn_mfma_f32_16x16x32_bf16(ra[s], rlb[s], accS, 0, 0, 0);
                    accS = __builtin_amdgcn_mfma_f32_16x16x32_bf16(rla[s], rb[s], accS, 0, 0, 0);
                }
            }
        } else {
            for (int it = 0; it < 4; ++it) {
                short8 ra[8], rb[8];
                #pragma unroll
                for (int s = 0; s < 8; ++s) {
                    const int c = it * 8 + s;           // kc-local 0..31
                    ra[s] = a8[(size_t)c * 64];
                    rb[s] = b8[c * 4];
                }
                #pragma unroll
                for (int s = 0; s < 8; ++s) {
                    if (s & 1) acc1 = __builtin_amdgcn_mfma_f32_16x16x32_bf16(ra[s], rb[s], acc1, 0, 0, 0);
                    else       acc0 = __builtin_amdgcn_mfma_f32_16x16x32_bf16(ra[s], rb[s], acc0, 0, 0, 0);
                }
            }
        }
        red[wave][lane] = acc0 + acc1 + accS;
        __syncthreads();
        if (tid < 64) {
            f32x4 v = red[0][tid] + red[1][tid] + red[2][tid] + red[3][tid];
            const int col = tid & 15;
            const int rb0 = row0 + ((tid >> 4) << 2);
            #pragma unroll
            for (int i = 0; i < 4; ++i) {
                WfOut[col * NDIM + rb0 + i] = v[i];
                __hip_bfloat16 h = __float2bfloat16(v[i]);
                WhOut[col * NDIM + rb0 + i] = h;
                if (SEED) WlOut[col * NDIM + rb0 + i] =
                    __float2bfloat16(v[i] - __bfloat162float(h));
            }
        }
    } else {
        // ---------------- R role ----------------
        if (!doR) return;
        const int tile = blockIdx.x - 256;   // rows [16*tile, 16*tile+16) of At
        const int rl   = tid >> 4;           // row_local 0..15
        const int l16  = tid & 15;
        const size_t rowg = (size_t)tile * 16 + rl;
        const short8* arow = (const short8*)(At + rowg * NDIM) + l16; // k = l16*8 + j*128
        const f32x4*  g4   = (const f32x4*)gIn + l16 * 2;
        float acc = 0.0f;
        #pragma unroll 4
        for (int j = 0; j < 32; ++j) {
            union { short8 s8; unsigned short u[8]; } ua;
            ua.s8 = arow[j * 16];
            f32x4 g0 = g4[j * 32];
            f32x4 g1 = g4[j * 32 + 1];
            #pragma unroll
            for (int e = 0; e < 4; ++e) {
                union { unsigned int u; float f; } c0, c1;
                c0.u = (unsigned int)ua.u[e]     << 16;
                c1.u = (unsigned int)ua.u[e + 4] << 16;
                acc += c0.f * g0[e] + c1.f * g1[e];
            }
        }
        #pragma unroll
        for (int off = 8; off > 0; off >>= 1) acc += __shfl_down(acc, off, 16);
        if (l16 == 0) gOut[rowg] = acc;
    }
}

// ---------- f_m for all m: m<=28 via C.W_m, m=28+i via g_i.W_28 ----------
__global__ __launch_bounds__(256) void k_fbatch(
        const float* __restrict__ Wall, const float* __restrict__ C,
        const float* __restrict__ gf, float* __restrict__ F) {
    const int m = blockIdx.x;             // 0..JT-1
    const float* W;
    const float* vec;
    if (m <= VAPPS) { W = Wall + (size_t)m * SLAB;     vec = C; }
    else           { W = Wall + (size_t)VAPPS * SLAB; vec = gf + (size_t)(m - VAPPS) * NDIM; }
    const int tid = threadIdx.x, lane = tid & 63, wave = tid >> 6;
    float acc[NC] = {};
    for (int k = tid; k < NDIM; k += 256) {
        float ck = vec[k];
        #pragma unroll
        for (int c = 0; c < NC; ++c) acc[c] += ck * W[c * NDIM + k];
    }
    __shared__ float red[4][NC];
    #pragma unroll
    for (int c = 0; c < NC; ++c) {
        float s = acc[c];
        #pragma unroll
        for (int off = 32; off > 0; off >>= 1) s += __shfl_down(s, off);
        if (lane == 0) red[wave][c] = s;
    }
    __syncthreads();
    if (tid < NC) F[m * NC + tid] = red[0][tid] + red[1][tid] + red[2][tid] + red[3][tid];
}

// ---------- causal convolution + tanh epilogue ----------
__global__ __launch_bounds__(256) void k_conv(
        const float* __restrict__ F, const float* __restrict__ u,
        const float* __restrict__ yobs, const float* __restrict__ Dm,
        float* __restrict__ out) {
    __shared__ float Fl[JT * NC];
    __shared__ float zw[(JT + 256) * 9];
    const int tid = threadIdx.x;
    const int t0  = blockIdx.x * 256;
    for (int idx = tid; idx < JT * NC; idx += 256) Fl[idx] = F[idx];
    for (int idx = tid; idx < (JT + 256) * 9; idx += 256) {
        int k = idx / 9, c = idx - k * 9;
        int s = t0 - JT + k;
        float v = 0.0f;
        if (s >= 0 && s < NDIM) v = (c < 8) ? u[c * NDIM + s] : yobs[s];
        zw[idx] = v;
    }
    __syncthreads();
    const int t = t0 + tid;
    float y = (t < JT) ? Fl[t * NC + 9] : 0.0f; // C A'^t h0 term (truncated)
    #pragma unroll
    for (int c = 0; c < 8; ++c) y += Dm[c] * u[c * NDIM + t];
    for (int j = 0; j < JT; ++j) { // s = t-1-j; s<0 hits zero pad
        const float* fj = Fl + j * NC;
        const float* zz = zw + (tid + JT - 1 - j) * 9;
        float p = 0.0f;
        #pragma unroll
        for (int c = 0; c < 9; ++c) p += fj[c] * zz[c];
        y += p;
    }
    out[t] = 3.0f * tanhf(y);
}

extern "C" void kernel_launch(void* const* d_in, const int* in_sizes, int n_in,
                              void* d_out, int out_size, void* d_ws, size_t ws_size,
                              hipStream_t stream) {
    const float* u    = (const float*)d_in[0];
    const float* yobs = (const float*)d_in[1];
    const float* A    = (const float*)d_in[2];
    const float* Bm   = (const float*)d_in[3];
    const float* C    = (const float*)d_in[4];
    const float* Dm   = (const float*)d_in[5];
    const float* L    = (const float*)d_in[6];
    float* out = (float*)d_out;

    // workspace layout (~113.4 MB)
    char* ws = (char*)d_ws;
    short8*         AhSw = (short8*)ws;                               // 32 MB
    short8*         AlSw = (short8*)(ws + 33554432ull);               // 32 MB
    __hip_bfloat16* At   = (__hip_bfloat16*)(ws + 67108864ull);       // 32 MB
    float*          Wf   = (float*)(ws + 100663296ull);               // 29*256 KB
    __hip_bfloat16* Wh   = (__hip_bfloat16*)(ws + 108265472ull);      // 29*128 KB
    __hip_bfloat16* Wl   = (__hip_bfloat16*)(ws + 112066560ull);      // 7*128 KB
    float*          gf   = (float*)(ws + 112984064ull);               // 28*16 KB
    float*          F    = (float*)(ws + 113442816ull);               // 2.24 KB

    k_build_a<<<dim3(TILES * KC * 64 / 256), dim3(256), 0, stream>>>(A, C, L, AhSw, AlSw);
    k_build_at<<<dim3(64 * 64), dim3(256), 0, stream>>>(A, C, L, At);
    k_build_w0<<<dim3(16), dim3(256), 0, stream>>>(Bm, Dm, L, C, Wf, Wh, Wl, gf);

    for (int r = 0; r < VAPPS; ++r) {
        const size_t in  = (size_t)r * SLAB;
        const size_t out_ = (size_t)(r + 1) * SLAB;
        const int doR = (r < RAPPS) ? 1 : 0;
        if (r < SEEDS)
            k_stepVR<true><<<dim3(512), dim3(256), 0, stream>>>(
                AhSw, AlSw, Wh + in, Wl + in,
                Wf + out_, Wh + out_, Wl + out_,
                At, gf + (size_t)r * NDIM, gf + (size_t)(r + 1) * NDIM, doR);
        else
            k_stepVR<false><<<dim3(512), dim3(256), 0, stream>>>(
                AhSw, nullptr, Wh + in, nullptr,
                Wf + out_, Wh + out_, nullptr,
                At, gf + (size_t)r * NDIM, gf + (size_t)(r + 1) * NDIM, doR);
    }

    k_fbatch<<<dim3(JT), dim3(256), 0, stream>>>(Wf, C, gf, F);
    k_conv<<<dim3(16), dim3(256), 0, stream>>>(F, u, yobs, Dm, out);
}

// Round 4
// 482.602 us; speedup vs baseline: 8.6760x; 1.1046x over previous
//
#include <hip/hip_runtime.h>
#include <math.h>

// Observer recurrence -> LTI Markov-parameter convolution.
//   A' = A - L*C, K = [B - L*D | L | h0], f_m = C A'^m K
//   y_t = f_t[9] + D*u_t + sum_j f_j . z_{t-1-j};  out = 3*tanh(y)
// Round-12: the chain is REQUEST-bandwidth-bound (~6.4 TB/s effective; r10/r11
// proved launches and waves don't matter). Cut bytes:
//  (a) bf16 -> fp16 chain-wide: same 2 B, 10-bit mantissa (8x finer). This
//      obsoletes the split-precision seed machinery: AlSw/Wl/SEEDS deleted
//      (was 6 launches reading double A+B). Accuracy strictly improves.
//  (b) dead-column skip: W cols 10..15 are identically zero; lanes mr>=10
//      skip the B-load (exec-masked, no requests) -> -37.5% B-broadcast.
//      Epilogue writes restricted to col<10. Bit-exact vs reading zeros.
//  (c) fused build: read fp32 A once, emit swizzled-fragment A' (fp16) and
//      transposed A' (fp16) in one kernel.
// Structure stays r11's meet-in-the-middle (28 launches, V+R roles):
// request/step drops 100->88 MB and seed surcharge vanishes.
// Predicted: 533 -> ~415-440 us, absmax <= 0.02.

constexpr int NDIM  = 4096;
constexpr int NC    = 10;         // live columns of K/W
constexpr int SLAB  = 16 * 4096;  // padded 16-col col-major slab (elements)
constexpr int JT    = 56;         // truncation length
constexpr int VAPPS = 28;         // V-chain applications (W_1..W_28)
constexpr int RAPPS = 27;         // R-chain applications (g_1..g_27)
constexpr int KC    = NDIM / 32;  // 128 k-chunks of 32
constexpr int TILES = NDIM / 16;  // 256 row-tiles of 16

typedef float    f32x4  __attribute__((ext_vector_type(4)));
typedef _Float16 h16x8  __attribute__((ext_vector_type(8)));
typedef _Float16 f16;

// ---------- fused build: A' = A - L*C -> AhSw (frag order) + At (transpose) --
// 64x64 fp32 tile through LDS; read A once (64 MB total vs 128 MB split).
// AhSw element (h16x8): idx = (tile*KC + kc)*64 + lane,
//   lane = mr + 16q holds A'[tile*16+mr][kc*32 + q*8 .. +7]
__global__ __launch_bounds__(256) void k_build_a(
        const float* __restrict__ A, const float* __restrict__ C,
        const float* __restrict__ L,
        h16x8* __restrict__ AhSw, f16* __restrict__ At) {
    __shared__ float lds[64][65];
    const int R0 = (blockIdx.x & 63) * 64;   // A row-block
    const int C0 = (blockIdx.x >> 6) * 64;   // A col-block
    const int tid = threadIdx.x;
    #pragma unroll
    for (int it = 0; it < 16; ++it) {
        const int r = it * 4 + (tid >> 6);
        const int c = tid & 63;
        lds[r][c] = A[(size_t)(R0 + r) * NDIM + C0 + c]
                  - L[R0 + r] * C[C0 + c];
    }
    __syncthreads();
    // transpose output (row-major At[c][r], coalesced in r)
    #pragma unroll
    for (int it = 0; it < 16; ++it) {
        const int c = it * 4 + (tid >> 6);
        const int r = tid & 63;
        At[(size_t)(C0 + c) * NDIM + R0 + r] = (f16)lds[r][c];
    }
    // swizzled-fragment output: 512 h16x8 per 64x64 region, 2 per thread
    #pragma unroll
    for (int half = 0; half < 2; ++half) {
        const int o = half * 256 + tid;      // 0..511
        const int r = o >> 3;                // 0..63
        const int g = o & 7;                 // 8-col group
        union { h16x8 v; f16 h[8]; } pk;
        #pragma unroll
        for (int j = 0; j < 8; ++j) pk.h[j] = (f16)lds[r][g * 8 + j];
        const int tile = (R0 >> 4) + (r >> 4);
        const int kc   = (C0 >> 5) + (g >> 2);
        const int lane = (r & 15) | ((g & 3) << 4);
        AhSw[((size_t)tile * KC + kc) * 64 + lane] = pk.v;
    }
}

// ---------- W0 = K = [B-L*D | L | ones | 0-pad], fp32 + fp16; g0 = C ----------
__global__ __launch_bounds__(256) void k_build_w0(
        const float* __restrict__ Bm, const float* __restrict__ Dm,
        const float* __restrict__ L, const float* __restrict__ C,
        float* __restrict__ Wf, f16* __restrict__ Wh, float* __restrict__ gf) {
    int k = blockIdx.x * blockDim.x + threadIdx.x; // < 4096
    float Lk = L[k];
    float col[16];
    #pragma unroll
    for (int c = 0; c < 8; ++c) col[c] = Bm[k * 8 + c] - Lk * Dm[c];
    col[8] = Lk; col[9] = 1.0f;
    #pragma unroll
    for (int c = 10; c < 16; ++c) col[c] = 0.0f;
    #pragma unroll
    for (int c = 0; c < 16; ++c) {
        Wf[c * NDIM + k] = col[c];
        Wh[c * NDIM + k] = (f16)col[c];
    }
    gf[k] = C[k];   // g_0 = C
}

// ---------- fused step: V-role (blocks 0..255) + R-role (blocks 256..511) --
// V: W_{m+1} = A' W_m, 4 waves, k-split 4x1024, fp16 MFMA.
//    B-loads predicated on mr<10 (cols 10..15 are identically zero).
// R: g_{r+1}[k'] = sum_k At[k'][k] * g_r[k], fp32 carry, fp16 At rows.
__global__ __launch_bounds__(256) void k_stepVR(
        const h16x8* __restrict__ AhSw, const f16* __restrict__ At,
        const f16* __restrict__ WhIn,
        float* __restrict__ WfOut, f16* __restrict__ WhOut,
        const float* __restrict__ gIn, float* __restrict__ gOut,
        const int doR) {
    __shared__ f32x4 red[4][64];
    const int tid = threadIdx.x;

    if (blockIdx.x < 256) {
        // ---------------- V role ----------------
        const int lane = tid & 63, wave = tid >> 6;
        const int mr   = lane & 15, q = lane >> 4;
        const int tile = blockIdx.x;
        const int row0 = tile * 16;
        const int k0   = wave * 1024;
        const bool liveB = (mr < NC);
        const h16x8* a8 = AhSw + ((size_t)tile * KC + wave * 32) * 64 + lane;
        const h16x8* b8 = (const h16x8*)WhIn + (((size_t)mr * NDIM + k0) >> 3) + q;

        f32x4 acc0 = {0,0,0,0}, acc1 = {0,0,0,0};
        for (int it = 0; it < 4; ++it) {
            h16x8 ra[8], rb[8];
            #pragma unroll
            for (int s = 0; s < 8; ++s) rb[s] = (h16x8){0,0,0,0,0,0,0,0};
            #pragma unroll
            for (int s = 0; s < 8; ++s) {
                const int c = it * 8 + s;           // kc-local 0..31
                ra[s] = a8[(size_t)c * 64];
            }
            if (liveB) {
                #pragma unroll
                for (int s = 0; s < 8; ++s) {
                    const int c = it * 8 + s;
                    rb[s] = b8[c * 4];
                }
            }
            #pragma unroll
            for (int s = 0; s < 8; ++s) {
                if (s & 1) acc1 = __builtin_amdgcn_mfma_f32_16x16x32_f16(ra[s], rb[s], acc1, 0, 0, 0);
                else       acc0 = __builtin_amdgcn_mfma_f32_16x16x32_f16(ra[s], rb[s], acc0, 0, 0, 0);
            }
        }
        red[wave][lane] = acc0 + acc1;
        __syncthreads();
        if (tid < 64) {
            f32x4 v = red[0][tid] + red[1][tid] + red[2][tid] + red[3][tid];
            const int col = tid & 15;
            if (col < NC) {
                const int rb0 = row0 + ((tid >> 4) << 2);
                #pragma unroll
                for (int i = 0; i < 4; ++i) {
                    WfOut[col * NDIM + rb0 + i] = v[i];
                    WhOut[col * NDIM + rb0 + i] = (f16)v[i];
                }
            }
        }
    } else {
        // ---------------- R role ----------------
        if (!doR) return;
        const int tile = blockIdx.x - 256;   // rows [16*tile, 16*tile+16) of At
        const int rl   = tid >> 4;           // row_local 0..15
        const int l16  = tid & 15;
        const size_t rowg = (size_t)tile * 16 + rl;
        const h16x8* arow = (const h16x8*)(At + rowg * NDIM) + l16; // k = l16*8 + j*128
        const f32x4* g4   = (const f32x4*)gIn + l16 * 2;
        float acc = 0.0f;
        #pragma unroll 4
        for (int j = 0; j < 32; ++j) {
            union { h16x8 v; f16 h[8]; } ua;
            ua.v = arow[j * 16];
            f32x4 g0 = g4[j * 32];
            f32x4 g1 = g4[j * 32 + 1];
            #pragma unroll
            for (int e = 0; e < 4; ++e)
                acc += (float)ua.h[e] * g0[e] + (float)ua.h[e + 4] * g1[e];
        }
        #pragma unroll
        for (int off = 8; off > 0; off >>= 1) acc += __shfl_down(acc, off, 16);
        if (l16 == 0) gOut[rowg] = acc;
    }
}

// ---------- f_m for all m: m<=28 via C.W_m, m=28+i via g_i.W_28 ----------
__global__ __launch_bounds__(256) void k_fbatch(
        const float* __restrict__ Wall, const float* __restrict__ C,
        const float* __restrict__ gf, float* __restrict__ F) {
    const int m = blockIdx.x;             // 0..JT-1
    const float* W;
    const float* vec;
    if (m <= VAPPS) { W = Wall + (size_t)m * SLAB;     vec = C; }
    else            { W = Wall + (size_t)VAPPS * SLAB; vec = gf + (size_t)(m - VAPPS) * NDIM; }
    const int tid = threadIdx.x, lane = tid & 63, wave = tid >> 6;
    float acc[NC] = {};
    for (int k = tid; k < NDIM; k += 256) {
        float ck = vec[k];
        #pragma unroll
        for (int c = 0; c < NC; ++c) acc[c] += ck * W[c * NDIM + k];
    }
    __shared__ float red[4][NC];
    #pragma unroll
    for (int c = 0; c < NC; ++c) {
        float s = acc[c];
        #pragma unroll
        for (int off = 32; off > 0; off >>= 1) s += __shfl_down(s, off);
        if (lane == 0) red[wave][c] = s;
    }
    __syncthreads();
    if (tid < NC) F[m * NC + tid] = red[0][tid] + red[1][tid] + red[2][tid] + red[3][tid];
}

// ---------- causal convolution + tanh epilogue ----------
__global__ __launch_bounds__(256) void k_conv(
        const float* __restrict__ F, const float* __restrict__ u,
        const float* __restrict__ yobs, const float* __restrict__ Dm,
        float* __restrict__ out) {
    __shared__ float Fl[JT * NC];
    __shared__ float zw[(JT + 256) * 9];
    const int tid = threadIdx.x;
    const int t0  = blockIdx.x * 256;
    for (int idx = tid; idx < JT * NC; idx += 256) Fl[idx] = F[idx];
    for (int idx = tid; idx < (JT + 256) * 9; idx += 256) {
        int k = idx / 9, c = idx - k * 9;
        int s = t0 - JT + k;
        float v = 0.0f;
        if (s >= 0 && s < NDIM) v = (c < 8) ? u[c * NDIM + s] : yobs[s];
        zw[idx] = v;
    }
    __syncthreads();
    const int t = t0 + tid;
    float y = (t < JT) ? Fl[t * NC + 9] : 0.0f; // C A'^t h0 term (truncated)
    #pragma unroll
    for (int c = 0; c < 8; ++c) y += Dm[c] * u[c * NDIM + t];
    for (int j = 0; j < JT; ++j) { // s = t-1-j; s<0 hits zero pad
        const float* fj = Fl + j * NC;
        const float* zz = zw + (tid + JT - 1 - j) * 9;
        float p = 0.0f;
        #pragma unroll
        for (int c = 0; c < 9; ++c) p += fj[c] * zz[c];
        y += p;
    }
    out[t] = 3.0f * tanhf(y);
}

extern "C" void kernel_launch(void* const* d_in, const int* in_sizes, int n_in,
                              void* d_out, int out_size, void* d_ws, size_t ws_size,
                              hipStream_t stream) {
    const float* u    = (const float*)d_in[0];
    const float* yobs = (const float*)d_in[1];
    const float* A    = (const float*)d_in[2];
    const float* Bm   = (const float*)d_in[3];
    const float* C    = (const float*)d_in[4];
    const float* Dm   = (const float*)d_in[5];
    const float* L    = (const float*)d_in[6];
    float* out = (float*)d_out;

    // workspace layout (~79 MB)
    char* ws = (char*)d_ws;
    h16x8* AhSw = (h16x8*)ws;                         // 32 MB
    f16*   At   = (f16*)(ws + 33554432ull);           // 32 MB
    float* Wf   = (float*)(ws + 67108864ull);         // 29*256 KB
    f16*   Wh   = (f16*)(ws + 74711040ull);           // 29*128 KB
    float* gf   = (float*)(ws + 78512128ull);         // 28*16 KB
    float* F    = (float*)(ws + 78970880ull);         // 2.24 KB

    k_build_a<<<dim3(64 * 64), dim3(256), 0, stream>>>(A, C, L, AhSw, At);
    k_build_w0<<<dim3(16), dim3(256), 0, stream>>>(Bm, Dm, L, C, Wf, Wh, gf);

    for (int r = 0; r < VAPPS; ++r) {
        const size_t in   = (size_t)r * SLAB;
        const size_t out_ = (size_t)(r + 1) * SLAB;
        const int doR = (r < RAPPS) ? 1 : 0;
        k_stepVR<<<dim3(512), dim3(256), 0, stream>>>(
            AhSw, At, Wh + in, Wf + out_, Wh + out_,
            gf + (size_t)r * NDIM, gf + (size_t)(r + 1) * NDIM, doR);
    }

    k_fbatch<<<dim3(JT), dim3(256), 0, stream>>>(Wf, C, gf, F);
    k_conv<<<dim3(16), dim3(256), 0, stream>>>(F, u, yobs, Dm, out);
}

// Round 5
// 470.803 us; speedup vs baseline: 8.8934x; 1.0251x over previous
//
#include <hip/hip_runtime.h>
#include <math.h>

// Observer recurrence -> LTI Markov-parameter convolution.
//   A' = A - L*C, K = [B - L*D | L | h0], f_m = C A'^m K
//   y_t = f_t[9] + D*u_t + sum_j f_j . z_{t-1-j};  out = 3*tanh(y)
// Round-13: delete the At transpose array. r12's chain footprint was
// AhSw(32MB)+At(32MB) = 8 MB/XCD = 2x the 4 MB per-XCD L2 -> every step
// streamed A from L3. Now the R-chain (g_{r+1} = A'^T g_r) reads the SAME
// swizzled AhSw fragments: group (tile,ch) = 16 contiguous h16x8 covering
// rows 0..15 x cols [8ch,8ch+8), so R-block t computes its 16-row partial
// part[col] = sum_row g[row]*A'[row][col] with zero cross-lane work and
// writes Rpart[t][0..4096) (16 KB). Next step reduces the 256x16 slice in
// LDS. A-footprint halves to 4 MB/XCD (L2-fit); V-block t and R-block
// 256+t share an XCD (stable %8 mapping) so R's read is L2-hot.
// V-side math unchanged from r12 (fp16 MFMA, dead-col skip). JT=56.

constexpr int NDIM  = 4096;
constexpr int NC    = 10;         // live columns of K/W
constexpr int SLAB  = 16 * 4096;  // padded 16-col col-major slab (elements)
constexpr int JT    = 56;         // truncation length
constexpr int VAPPS = 28;         // V-chain applications (W_1..W_28)
constexpr int KC    = NDIM / 32;  // 128 k-chunks of 32
constexpr int TILES = NDIM / 16;  // 256 row-tiles of 16

typedef float    f32x4  __attribute__((ext_vector_type(4)));
typedef _Float16 h16x8  __attribute__((ext_vector_type(8)));
typedef _Float16 f16;

// ---------- build A' = A - L*C, fp16, swizzled to fragment order ----------
// AhSw element (h16x8): idx = (tile*KC + kc)*64 + lane
//   lane = mr + 16q holds A'[tile*16+mr][kc*32 + q*8 .. +7]
__global__ __launch_bounds__(256) void k_build_a(
        const float* __restrict__ A, const float* __restrict__ C,
        const float* __restrict__ L, h16x8* __restrict__ AhSw) {
    const size_t idx = (size_t)blockIdx.x * blockDim.x + threadIdx.x; // < TILES*KC*64
    const int lane = (int)(idx & 63);
    const int kc   = (int)((idx >> 6) & (KC - 1));
    const int tile = (int)(idx >> 13);
    const int row  = tile * 16 + (lane & 15);
    const int col  = kc * 32 + (lane >> 4) * 8;
    const float4 a0 = *(const float4*)(A + (size_t)row * NDIM + col);
    const float4 a1 = *(const float4*)(A + (size_t)row * NDIM + col + 4);
    const float Li = L[row];
    union { h16x8 v; f16 h[8]; } pk;
    pk.h[0] = (f16)(a0.x - Li * C[col + 0]);
    pk.h[1] = (f16)(a0.y - Li * C[col + 1]);
    pk.h[2] = (f16)(a0.z - Li * C[col + 2]);
    pk.h[3] = (f16)(a0.w - Li * C[col + 3]);
    pk.h[4] = (f16)(a1.x - Li * C[col + 4]);
    pk.h[5] = (f16)(a1.y - Li * C[col + 5]);
    pk.h[6] = (f16)(a1.z - Li * C[col + 6]);
    pk.h[7] = (f16)(a1.w - Li * C[col + 7]);
    AhSw[idx] = pk.v;
}

// ---------- W0 = K = [B-L*D | L | ones | 0-pad], fp32 + fp16 ----------
__global__ __launch_bounds__(256) void k_build_w0(
        const float* __restrict__ Bm, const float* __restrict__ Dm,
        const float* __restrict__ L,
        float* __restrict__ Wf, f16* __restrict__ Wh) {
    int k = blockIdx.x * blockDim.x + threadIdx.x; // < 4096
    float Lk = L[k];
    float col[16];
    #pragma unroll
    for (int c = 0; c < 8; ++c) col[c] = Bm[k * 8 + c] - Lk * Dm[c];
    col[8] = Lk; col[9] = 1.0f;
    #pragma unroll
    for (int c = 10; c < 16; ++c) col[c] = 0.0f;
    #pragma unroll
    for (int c = 0; c < 16; ++c) {
        Wf[c * NDIM + k] = col[c];
        Wh[c * NDIM + k] = (f16)col[c];
    }
}

// ---------- fused step: V-role (blocks 0..255) + R-role (blocks 256..511) --
// V: W_{m+1} = A' W_m; 4 waves, k-split 4x1024, fp16 MFMA, dead-col skip.
// R: block t: (a) g_r slice = reduce(RpartIn[0..256][t*16..]) (or C at r=0),
//    (b) store slice to gf[r], (c) if r<VAPPS-1: Rpart[t][col] =
//    sum_{row in tile t} g_r[row]*A'[row][col] from the SAME AhSw fragments.
__global__ __launch_bounds__(256) void k_stepVR(
        const h16x8* __restrict__ AhSw, const f16* __restrict__ WhIn,
        float* __restrict__ WfOut, f16* __restrict__ WhOut,
        const float* __restrict__ Cvec,
        const float* __restrict__ RpartIn, float* __restrict__ RpartOut,
        float* __restrict__ gfSlot, const int r) {
    const int tid = threadIdx.x;

    if (blockIdx.x < 256) {
        // ---------------- V role ----------------
        __shared__ f32x4 red[4][64];
        const int lane = tid & 63, wave = tid >> 6;
        const int mr   = lane & 15, q = lane >> 4;
        const int tile = blockIdx.x;
        const int row0 = tile * 16;
        const int k0   = wave * 1024;
        const bool liveB = (mr < NC);
        const h16x8* a8 = AhSw + ((size_t)tile * KC + wave * 32) * 64 + lane;
        const h16x8* b8 = (const h16x8*)WhIn + (((size_t)mr * NDIM + k0) >> 3) + q;

        f32x4 acc0 = {0,0,0,0}, acc1 = {0,0,0,0};
        for (int it = 0; it < 4; ++it) {
            h16x8 ra[8], rb[8];
            #pragma unroll
            for (int s = 0; s < 8; ++s) rb[s] = (h16x8){0,0,0,0,0,0,0,0};
            #pragma unroll
            for (int s = 0; s < 8; ++s) {
                const int c = it * 8 + s;           // kc-local 0..31
                ra[s] = a8[(size_t)c * 64];
            }
            if (liveB) {
                #pragma unroll
                for (int s = 0; s < 8; ++s) {
                    const int c = it * 8 + s;
                    rb[s] = b8[c * 4];
                }
            }
            #pragma unroll
            for (int s = 0; s < 8; ++s) {
                if (s & 1) acc1 = __builtin_amdgcn_mfma_f32_16x16x32_f16(ra[s], rb[s], acc1, 0, 0, 0);
                else       acc0 = __builtin_amdgcn_mfma_f32_16x16x32_f16(ra[s], rb[s], acc0, 0, 0, 0);
            }
        }
        red[wave][lane] = acc0 + acc1;
        __syncthreads();
        if (tid < 64) {
            f32x4 v = red[0][tid] + red[1][tid] + red[2][tid] + red[3][tid];
            const int col = tid & 15;
            if (col < NC) {
                const int rb0 = row0 + ((tid >> 4) << 2);
                #pragma unroll
                for (int i = 0; i < 4; ++i) {
                    WfOut[col * NDIM + rb0 + i] = v[i];
                    WhOut[col * NDIM + rb0 + i] = (f16)v[i];
                }
            }
        }
    } else {
        // ---------------- R role ----------------
        __shared__ float rp[256][17];
        __shared__ float g2[16][17];
        __shared__ float gs[16];
        const int t = blockIdx.x - 256;

        // (a) obtain g_r slice for rows [16t, 16t+16)
        if (r == 0) {
            if (tid < 16) gs[tid] = Cvec[t * 16 + tid];
        } else {
            const float* src = RpartIn + (size_t)tid * NDIM + t * 16;
            #pragma unroll
            for (int j = 0; j < 16; j += 4) {
                float4 v = *(const float4*)(src + j);
                rp[tid][j] = v.x; rp[tid][j+1] = v.y;
                rp[tid][j+2] = v.z; rp[tid][j+3] = v.w;
            }
            __syncthreads();
            {
                const int c = tid & 15, g = tid >> 4;   // g: 0..15
                float p = 0.0f;
                #pragma unroll
                for (int j = 0; j < 16; ++j) p += rp[g * 16 + j][c];
                g2[g][c] = p;
            }
            __syncthreads();
            if (tid < 16) {
                float s = 0.0f;
                #pragma unroll
                for (int g = 0; g < 16; ++g) s += g2[g][tid];
                gs[tid] = s;
            }
        }
        __syncthreads();
        if (tid < 16) gfSlot[t * 16 + tid] = gs[tid];

        // (c) partials for g_{r+1}
        if (r < VAPPS - 1) {
            float gloc[16];
            #pragma unroll
            for (int j = 0; j < 16; ++j) gloc[j] = gs[j];
            const h16x8* base = AhSw + (size_t)t * (KC * 64);
            #pragma unroll
            for (int cc = 0; cc < 2; ++cc) {
                const int ch = tid * 2 + cc;            // 0..511, cols [8ch,8ch+8)
                const h16x8* fr = base + (size_t)ch * 16;
                float acc[8] = {};
                #pragma unroll
                for (int mrr = 0; mrr < 16; ++mrr) {
                    union { h16x8 v; f16 h[8]; } ua;
                    ua.v = fr[mrr];
                    const float gm = gloc[mrr];
                    #pragma unroll
                    for (int j = 0; j < 8; ++j) acc[j] += gm * (float)ua.h[j];
                }
                float4* op = (float4*)(RpartOut + (size_t)t * NDIM + 8 * ch);
                op[0] = make_float4(acc[0], acc[1], acc[2], acc[3]);
                op[1] = make_float4(acc[4], acc[5], acc[6], acc[7]);
            }
        }
    }
}

// ---------- f_m for all m: m<=28 via C.W_m, m=28+i via g_i.W_28 ----------
__global__ __launch_bounds__(256) void k_fbatch(
        const float* __restrict__ Wall, const float* __restrict__ C,
        const float* __restrict__ gf, float* __restrict__ F) {
    const int m = blockIdx.x;             // 0..JT-1
    const float* W;
    const float* vec;
    if (m <= VAPPS) { W = Wall + (size_t)m * SLAB;     vec = C; }
    else            { W = Wall + (size_t)VAPPS * SLAB; vec = gf + (size_t)(m - VAPPS) * NDIM; }
    const int tid = threadIdx.x, lane = tid & 63, wave = tid >> 6;
    float acc[NC] = {};
    for (int k = tid; k < NDIM; k += 256) {
        float ck = vec[k];
        #pragma unroll
        for (int c = 0; c < NC; ++c) acc[c] += ck * W[c * NDIM + k];
    }
    __shared__ float red[4][NC];
    #pragma unroll
    for (int c = 0; c < NC; ++c) {
        float s = acc[c];
        #pragma unroll
        for (int off = 32; off > 0; off >>= 1) s += __shfl_down(s, off);
        if (lane == 0) red[wave][c] = s;
    }
    __syncthreads();
    if (tid < NC) F[m * NC + tid] = red[0][tid] + red[1][tid] + red[2][tid] + red[3][tid];
}

// ---------- causal convolution + tanh epilogue ----------
__global__ __launch_bounds__(256) void k_conv(
        const float* __restrict__ F, const float* __restrict__ u,
        const float* __restrict__ yobs, const float* __restrict__ Dm,
        float* __restrict__ out) {
    __shared__ float Fl[JT * NC];
    __shared__ float zw[(JT + 256) * 9];
    const int tid = threadIdx.x;
    const int t0  = blockIdx.x * 256;
    for (int idx = tid; idx < JT * NC; idx += 256) Fl[idx] = F[idx];
    for (int idx = tid; idx < (JT + 256) * 9; idx += 256) {
        int k = idx / 9, c = idx - k * 9;
        int s = t0 - JT + k;
        float v = 0.0f;
        if (s >= 0 && s < NDIM) v = (c < 8) ? u[c * NDIM + s] : yobs[s];
        zw[idx] = v;
    }
    __syncthreads();
    const int t = t0 + tid;
    float y = (t < JT) ? Fl[t * NC + 9] : 0.0f; // C A'^t h0 term (truncated)
    #pragma unroll
    for (int c = 0; c < 8; ++c) y += Dm[c] * u[c * NDIM + t];
    for (int j = 0; j < JT; ++j) { // s = t-1-j; s<0 hits zero pad
        const float* fj = Fl + j * NC;
        const float* zz = zw + (tid + JT - 1 - j) * 9;
        float p = 0.0f;
        #pragma unroll
        for (int c = 0; c < 9; ++c) p += fj[c] * zz[c];
        y += p;
    }
    out[t] = 3.0f * tanhf(y);
}

extern "C" void kernel_launch(void* const* d_in, const int* in_sizes, int n_in,
                              void* d_out, int out_size, void* d_ws, size_t ws_size,
                              hipStream_t stream) {
    const float* u    = (const float*)d_in[0];
    const float* yobs = (const float*)d_in[1];
    const float* A    = (const float*)d_in[2];
    const float* Bm   = (const float*)d_in[3];
    const float* C    = (const float*)d_in[4];
    const float* Dm   = (const float*)d_in[5];
    const float* L    = (const float*)d_in[6];
    float* out = (float*)d_out;

    // workspace layout (~54 MB)
    char* ws = (char*)d_ws;
    h16x8* AhSw  = (h16x8*)ws;                        // 32 MB
    float* Wf    = (float*)(ws + 33554432ull);        // 29*256 KB
    f16*   Wh    = (f16*)(ws + 41156608ull);          // 29*128 KB
    float* gf    = (float*)(ws + 44957696ull);        // 28*16 KB
    float* Rpart = (float*)(ws + 45416448ull);        // 2 * 4 MB (ping-pong)
    float* F     = (float*)(ws + 53805056ull);        // 2.24 KB

    constexpr size_t RPN = (size_t)256 * NDIM;        // one Rpart buffer (elems)

    k_build_a<<<dim3(TILES * KC * 64 / 256), dim3(256), 0, stream>>>(A, C, L, AhSw);
    k_build_w0<<<dim3(16), dim3(256), 0, stream>>>(Bm, Dm, L, Wf, Wh);

    for (int r = 0; r < VAPPS; ++r) {
        const size_t in   = (size_t)r * SLAB;
        const size_t out_ = (size_t)(r + 1) * SLAB;
        const float* rin  = Rpart + ((r + 1) & 1) * RPN;
        float*       rout = Rpart + (r & 1) * RPN;
        k_stepVR<<<dim3(512), dim3(256), 0, stream>>>(
            AhSw, Wh + in, Wf + out_, Wh + out_,
            C, rin, rout, gf + (size_t)r * NDIM, r);
    }

    k_fbatch<<<dim3(JT), dim3(256), 0, stream>>>(Wf, C, gf, F);
    k_conv<<<dim3(16), dim3(256), 0, stream>>>(F, u, yobs, Dm, out);
}

// Round 6
// 462.285 us; speedup vs baseline: 9.0573x; 1.0184x over previous
//
#include <hip/hip_runtime.h>
#include <math.h>

// Observer recurrence -> LTI Markov-parameter convolution.
//   A' = A - L*C, K = [B - L*D | L | h0], f_m = C A'^m K
//   y_t = f_t[9] + D*u_t + sum_j f_j . z_{t-1-j};  out = 3*tanh(y)
// Round-14: request-byte cuts. r5 post-mortem: step time = total L2-request
// bytes at ~6.4 TB/s regardless of hit tier (92 MB/step -> 14.4us). The A
// floor (2 roles x 32 MB) is fixed; cut the rest:
//  (a) V-side: 128 blocks x 2 tiles. Waves (0,2)/(1,3) read IDENTICAL B
//      streams (same k-half, different tile) -> 2nd wave hits per-CU L1.
//      B-broadcast misses 21 -> 10.5 MB/step.
//  (b) R-side: 128 blocks x 32 rows -> Rpart [128][4096]: 8 -> 4 MB/step.
//  (c) build: LDS-staged coalesced A-read (r5's direct build read A in 64B
//      row-strided segments, ~half-rate on 64 MB).
// Grid = 256 blocks = 1/CU; V-block t and R-block 128+t share an XCD (%8).
// Math identical to r12/r13 (fp16 chain, dead-col skip, MITM 28+27, JT=56).

constexpr int NDIM  = 4096;
constexpr int NC    = 10;         // live columns of K/W
constexpr int SLAB  = 16 * 4096;  // padded 16-col col-major slab (elements)
constexpr int JT    = 56;         // truncation length
constexpr int VAPPS = 28;         // V-chain applications (W_1..W_28)
constexpr int KC    = NDIM / 32;  // 128 k-chunks of 32
constexpr int TILES = NDIM / 16;  // 256 row-tiles of 16

typedef float    f32x4  __attribute__((ext_vector_type(4)));
typedef _Float16 h16x8  __attribute__((ext_vector_type(8)));
typedef _Float16 f16;

// ---------- build A' = A - L*C, fp16, swizzled to fragment order ----------
// AhSw element (h16x8): idx = (tile*KC + kc)*64 + lane
//   lane = mr + 16q holds A'[tile*16+mr][kc*32 + q*8 .. +7]
// LDS-staged: A read coalesced (256B segments), frags emitted from LDS.
__global__ __launch_bounds__(256) void k_build_a(
        const float* __restrict__ A, const float* __restrict__ C,
        const float* __restrict__ L, h16x8* __restrict__ AhSw) {
    __shared__ float lds[64][65];
    const int R0 = (blockIdx.x & 63) * 64;   // row-block
    const int C0 = (blockIdx.x >> 6) * 64;   // col-block
    const int tid = threadIdx.x;
    #pragma unroll
    for (int it = 0; it < 16; ++it) {
        const int r = it * 4 + (tid >> 6);
        const int c = tid & 63;
        lds[r][c] = A[(size_t)(R0 + r) * NDIM + C0 + c]
                  - L[R0 + r] * C[C0 + c];
    }
    __syncthreads();
    #pragma unroll
    for (int half = 0; half < 2; ++half) {
        const int o = half * 256 + tid;      // 0..511
        const int r = o >> 3;                // 0..63
        const int g = o & 7;                 // 8-col group
        union { h16x8 v; f16 h[8]; } pk;
        #pragma unroll
        for (int j = 0; j < 8; ++j) pk.h[j] = (f16)lds[r][g * 8 + j];
        const int tile = (R0 >> 4) + (r >> 4);
        const int kc   = (C0 >> 5) + (g >> 2);
        const int lane = (r & 15) | ((g & 3) << 4);
        AhSw[((size_t)tile * KC + kc) * 64 + lane] = pk.v;
    }
}

// ---------- W0 = K = [B-L*D | L | ones | 0-pad], fp32 + fp16 ----------
__global__ __launch_bounds__(256) void k_build_w0(
        const float* __restrict__ Bm, const float* __restrict__ Dm,
        const float* __restrict__ L,
        float* __restrict__ Wf, f16* __restrict__ Wh) {
    int k = blockIdx.x * blockDim.x + threadIdx.x; // < 4096
    float Lk = L[k];
    float col[16];
    #pragma unroll
    for (int c = 0; c < 8; ++c) col[c] = Bm[k * 8 + c] - Lk * Dm[c];
    col[8] = Lk; col[9] = 1.0f;
    #pragma unroll
    for (int c = 10; c < 16; ++c) col[c] = 0.0f;
    #pragma unroll
    for (int c = 0; c < 16; ++c) {
        Wf[c * NDIM + k] = col[c];
        Wh[c * NDIM + k] = (f16)col[c];
    }
}

// ---------- fused step: V-role (blocks 0..127) + R-role (blocks 128..255) --
// V: block tp owns tiles 2tp,2tp+1. wave w: tile 2tp+(w>>1), k-half (w&1).
//    Waves 0&2 (and 1&3) read identical B streams -> L1 sharing.
// R: block t owns rows [32t,32t+32): reduce 128 partials, emit g_r slice,
//    compute next partials from the SAME AhSw fragments (VALU, fp32 carry).
__global__ __launch_bounds__(256) void k_stepVR(
        const h16x8* __restrict__ AhSw, const f16* __restrict__ WhIn,
        float* __restrict__ WfOut, f16* __restrict__ WhOut,
        const float* __restrict__ Cvec,
        const float* __restrict__ RpartIn, float* __restrict__ RpartOut,
        float* __restrict__ gfSlot, const int r) {
    const int tid = threadIdx.x;

    if (blockIdx.x < 128) {
        // ---------------- V role ----------------
        __shared__ f32x4 red[4][64];
        const int lane = tid & 63, wave = tid >> 6;
        const int mr   = lane & 15, q = lane >> 4;
        const int tp   = blockIdx.x;
        const int tile = tp * 2 + (wave >> 1);
        const int kh   = wave & 1;
        const int k0   = kh * 2048;
        const bool liveB = (mr < NC);
        const h16x8* a8 = AhSw + ((size_t)tile * KC + kh * 64) * 64 + lane;
        const h16x8* b8 = (const h16x8*)WhIn + (((size_t)mr * NDIM + k0) >> 3) + q;

        f32x4 acc0 = {0,0,0,0}, acc1 = {0,0,0,0};
        for (int it = 0; it < 8; ++it) {
            h16x8 ra[8], rb[8];
            #pragma unroll
            for (int s = 0; s < 8; ++s) rb[s] = (h16x8){0,0,0,0,0,0,0,0};
            #pragma unroll
            for (int s = 0; s < 8; ++s) {
                const int c = it * 8 + s;           // kc-local 0..63
                ra[s] = a8[(size_t)c * 64];
            }
            if (liveB) {
                #pragma unroll
                for (int s = 0; s < 8; ++s) {
                    const int c = it * 8 + s;
                    rb[s] = b8[c * 4];
                }
            }
            #pragma unroll
            for (int s = 0; s < 8; ++s) {
                if (s & 1) acc1 = __builtin_amdgcn_mfma_f32_16x16x32_f16(ra[s], rb[s], acc1, 0, 0, 0);
                else       acc0 = __builtin_amdgcn_mfma_f32_16x16x32_f16(ra[s], rb[s], acc0, 0, 0, 0);
            }
        }
        red[wave][lane] = acc0 + acc1;
        __syncthreads();
        if (tid < 128) {
            const int half = tid >> 6;          // 0: tile 2tp, 1: tile 2tp+1
            const int l    = tid & 63;
            f32x4 v = red[half * 2][l] + red[half * 2 + 1][l];
            const int col = l & 15;
            if (col < NC) {
                const int row0 = (tp * 2 + half) * 16;
                const int rb0  = row0 + ((l >> 4) << 2);
                #pragma unroll
                for (int i = 0; i < 4; ++i) {
                    WfOut[col * NDIM + rb0 + i] = v[i];
                    WhOut[col * NDIM + rb0 + i] = (f16)v[i];
                }
            }
        }
    } else {
        // ---------------- R role ----------------
        __shared__ float rp[4096];      // [partial 128][col 32], 16 KB
        __shared__ float g8[8][33];
        __shared__ float gs[32];
        const int t = blockIdx.x - 128;  // rows [32t, 32t+32)

        if (r == 0) {
            if (tid < 32) gs[tid] = Cvec[t * 32 + tid];
        } else {
            #pragma unroll
            for (int i = 0; i < 16; ++i) {
                const int idx = tid + i * 256;
                rp[idx] = RpartIn[(size_t)(idx >> 5) * NDIM + t * 32 + (idx & 31)];
            }
            __syncthreads();
            {
                const int c = tid & 31, g = tid >> 5;   // 8 groups x 32 cols
                float s = 0.0f;
                #pragma unroll
                for (int j = 0; j < 16; ++j) s += rp[(g * 16 + j) * 32 + c];
                g8[g][c] = s;
            }
            __syncthreads();
            if (tid < 32) {
                float s = 0.0f;
                #pragma unroll
                for (int g = 0; g < 8; ++g) s += g8[g][tid];
                gs[tid] = s;
            }
        }
        __syncthreads();
        if (tid < 32) gfSlot[t * 32 + tid] = gs[tid];

        if (r < VAPPS - 1) {
            float gl[32];
            #pragma unroll
            for (int j = 0; j < 32; ++j) gl[j] = gs[j];
            #pragma unroll
            for (int cc = 0; cc < 2; ++cc) {
                const int ch = tid * 2 + cc;            // 0..511, cols [8ch,8ch+8)
                float acc[8] = {};
                #pragma unroll
                for (int tt = 0; tt < 2; ++tt) {
                    const h16x8* fr = AhSw + (size_t)(t * 2 + tt) * (KC * 64)
                                    + (size_t)ch * 16;
                    #pragma unroll
                    for (int mrr = 0; mrr < 16; ++mrr) {
                        union { h16x8 v; f16 h[8]; } ua;
                        ua.v = fr[mrr];
                        const float gm = gl[tt * 16 + mrr];
                        #pragma unroll
                        for (int j = 0; j < 8; ++j) acc[j] += gm * (float)ua.h[j];
                    }
                }
                float4* op = (float4*)(RpartOut + (size_t)t * NDIM + 8 * ch);
                op[0] = make_float4(acc[0], acc[1], acc[2], acc[3]);
                op[1] = make_float4(acc[4], acc[5], acc[6], acc[7]);
            }
        }
    }
}

// ---------- f_m for all m: m<=28 via C.W_m, m=28+i via g_i.W_28 ----------
__global__ __launch_bounds__(256) void k_fbatch(
        const float* __restrict__ Wall, const float* __restrict__ C,
        const float* __restrict__ gf, float* __restrict__ F) {
    const int m = blockIdx.x;             // 0..JT-1
    const float* W;
    const float* vec;
    if (m <= VAPPS) { W = Wall + (size_t)m * SLAB;     vec = C; }
    else            { W = Wall + (size_t)VAPPS * SLAB; vec = gf + (size_t)(m - VAPPS) * NDIM; }
    const int tid = threadIdx.x, lane = tid & 63, wave = tid >> 6;
    float acc[NC] = {};
    for (int k = tid; k < NDIM; k += 256) {
        float ck = vec[k];
        #pragma unroll
        for (int c = 0; c < NC; ++c) acc[c] += ck * W[c * NDIM + k];
    }
    __shared__ float red[4][NC];
    #pragma unroll
    for (int c = 0; c < NC; ++c) {
        float s = acc[c];
        #pragma unroll
        for (int off = 32; off > 0; off >>= 1) s += __shfl_down(s, off);
        if (lane == 0) red[wave][c] = s;
    }
    __syncthreads();
    if (tid < NC) F[m * NC + tid] = red[0][tid] + red[1][tid] + red[2][tid] + red[3][tid];
}

// ---------- causal convolution + tanh epilogue ----------
__global__ __launch_bounds__(256) void k_conv(
        const float* __restrict__ F, const float* __restrict__ u,
        const float* __restrict__ yobs, const float* __restrict__ Dm,
        float* __restrict__ out) {
    __shared__ float Fl[JT * NC];
    __shared__ float zw[(JT + 256) * 9];
    const int tid = threadIdx.x;
    const int t0  = blockIdx.x * 256;
    for (int idx = tid; idx < JT * NC; idx += 256) Fl[idx] = F[idx];
    for (int idx = tid; idx < (JT + 256) * 9; idx += 256) {
        int k = idx / 9, c = idx - k * 9;
        int s = t0 - JT + k;
        float v = 0.0f;
        if (s >= 0 && s < NDIM) v = (c < 8) ? u[c * NDIM + s] : yobs[s];
        zw[idx] = v;
    }
    __syncthreads();
    const int t = t0 + tid;
    float y = (t < JT) ? Fl[t * NC + 9] : 0.0f; // C A'^t h0 term (truncated)
    #pragma unroll
    for (int c = 0; c < 8; ++c) y += Dm[c] * u[c * NDIM + t];
    for (int j = 0; j < JT; ++j) { // s = t-1-j; s<0 hits zero pad
        const float* fj = Fl + j * NC;
        const float* zz = zw + (tid + JT - 1 - j) * 9;
        float p = 0.0f;
        #pragma unroll
        for (int c = 0; c < 9; ++c) p += fj[c] * zz[c];
        y += p;
    }
    out[t] = 3.0f * tanhf(y);
}

extern "C" void kernel_launch(void* const* d_in, const int* in_sizes, int n_in,
                              void* d_out, int out_size, void* d_ws, size_t ws_size,
                              hipStream_t stream) {
    const float* u    = (const float*)d_in[0];
    const float* yobs = (const float*)d_in[1];
    const float* A    = (const float*)d_in[2];
    const float* Bm   = (const float*)d_in[3];
    const float* C    = (const float*)d_in[4];
    const float* Dm   = (const float*)d_in[5];
    const float* L    = (const float*)d_in[6];
    float* out = (float*)d_out;

    // workspace layout (~50 MB)
    char* ws = (char*)d_ws;
    h16x8* AhSw  = (h16x8*)ws;                        // 32 MB
    float* Wf    = (float*)(ws + 33554432ull);        // 29*256 KB
    f16*   Wh    = (f16*)(ws + 41156608ull);          // 29*128 KB
    float* gf    = (float*)(ws + 44957696ull);        // 28*16 KB
    float* Rpart = (float*)(ws + 45416448ull);        // 2 * 2 MB (ping-pong)
    float* F     = (float*)(ws + 49610752ull);        // 2.24 KB

    constexpr size_t RPN = (size_t)128 * NDIM;        // one Rpart buffer (elems)

    k_build_a<<<dim3(64 * 64), dim3(256), 0, stream>>>(A, C, L, AhSw);
    k_build_w0<<<dim3(16), dim3(256), 0, stream>>>(Bm, Dm, L, Wf, Wh);

    for (int r = 0; r < VAPPS; ++r) {
        const size_t in   = (size_t)r * SLAB;
        const size_t out_ = (size_t)(r + 1) * SLAB;
        const float* rin  = Rpart + ((r + 1) & 1) * RPN;
        float*       rout = Rpart + (r & 1) * RPN;
        k_stepVR<<<dim3(256), dim3(256), 0, stream>>>(
            AhSw, Wh + in, Wf + out_, Wh + out_,
            C, rin, rout, gf + (size_t)r * NDIM, r);
    }

    k_fbatch<<<dim3(JT), dim3(256), 0, stream>>>(Wf, C, gf, F);
    k_conv<<<dim3(16), dim3(256), 0, stream>>>(F, u, yobs, Dm, out);
}